// Round 6
// baseline (70480.988 us; speedup 1.0000x reference)
//
#include <hip/hip_runtime.h>

// Model dims
#define BB 512
#define LL 128
#define HH 768
#define LHID 256
#define TCHUNK 16
#define NCHUNK 8

typedef _Float16 h8 __attribute__((ext_vector_type(8)));
typedef _Float16 h4 __attribute__((ext_vector_type(4)));
typedef float f16acc __attribute__((ext_vector_type(16)));
typedef float f4 __attribute__((ext_vector_type(4)));

#define APAD 72        // LDS row stride in halfs (gemm)
#define XSP 50331648   // 65536*768, one part of split x

__device__ __forceinline__ float fsig(float x) { return 1.f / (1.f + __expf(-x)); }
__device__ __forceinline__ float ftanh(float x) { return 1.f - 2.f / (__expf(2.f * x) + 1.f); }

// ---------------------------------------------------------------------------
// xsplit: x fp32 -> fp16 hi/lo parts
// ---------------------------------------------------------------------------
__global__ __launch_bounds__(256) void xsplit_kernel(
    const float* __restrict__ x, _Float16* __restrict__ xs) {
  size_t e = ((size_t)blockIdx.x * 256 + threadIdx.x) * 8;
  float4 a = *(const float4*)&x[e];
  float4 b = *(const float4*)&x[e + 4];
  h8 hi, lo;
  hi[0] = (_Float16)a.x; lo[0] = (_Float16)(a.x - (float)hi[0]);
  hi[1] = (_Float16)a.y; lo[1] = (_Float16)(a.y - (float)hi[1]);
  hi[2] = (_Float16)a.z; lo[2] = (_Float16)(a.z - (float)hi[2]);
  hi[3] = (_Float16)a.w; lo[3] = (_Float16)(a.w - (float)hi[3]);
  hi[4] = (_Float16)b.x; lo[4] = (_Float16)(b.x - (float)hi[4]);
  hi[5] = (_Float16)b.y; lo[5] = (_Float16)(b.y - (float)hi[5]);
  hi[6] = (_Float16)b.z; lo[6] = (_Float16)(b.z - (float)hi[6]);
  hi[7] = (_Float16)b.w; lo[7] = (_Float16)(b.w - (float)hi[7]);
  *(h8*)&xs[e] = hi;
  *(h8*)&xs[XSP + e] = lo;
}

// ---------------------------------------------------------------------------
// prep: weight transposes / fp16 splits / LSTM bias fuse
// wihs + biasg are pre-GATHERED: n' = u*4 + gate (so GEMM rows == gates layout)
// ---------------------------------------------------------------------------
__global__ __launch_bounds__(256) void prep_kernel(
    const float* __restrict__ w_ih, const float* __restrict__ w_hh,
    const float* __restrict__ b_ih, const float* __restrict__ b_hh,
    const float* __restrict__ w1, const float* __restrict__ w2, const float* __restrict__ w3,
    const float* __restrict__ w4,
    const float* __restrict__ fc1_w, const float* __restrict__ fc2_w, const float* __restrict__ fc3_w,
    float* __restrict__ w_q, float* __restrict__ biasg,
    _Float16* __restrict__ w1s, _Float16* __restrict__ wihs,
    float* __restrict__ w2t, float* __restrict__ w3t, float* __restrict__ w4t,
    float* __restrict__ fc1_wt, float* __restrict__ fc2_wt, float* __restrict__ fc3_wt) {
  int tid = blockIdx.x * 256 + threadIdx.x;  // grid = 5376*256 = 1376256
  if (tid < 1376256) {  // w1 [co][ci][dk] -> fp16 split hi/lo, layout [dk][co][ci], x64
    int dk = tid / 196608, r = tid % 196608, co = r / 768, ci = r % 768;
    float v = w1[((size_t)co * 768 + ci) * 7 + dk] * 64.f;
    _Float16 h = (_Float16)v;
    w1s[tid] = h;
    w1s[1376256 + tid] = (_Float16)(v - (float)h);
  }
  if (tid < 786432) {  // w_ih -> fp16 split hi/lo, x64, GATHERED rows n' = u*4+gate
    int np = tid / 768, k = tid % 768;
    int u = np >> 2, gate = np & 3;
    float v = w_ih[(size_t)(gate * 256 + u) * 768 + k] * 64.f;
    _Float16 h = (_Float16)v;
    wihs[tid] = h;
    wihs[786432 + tid] = (_Float16)(v - (float)h);
  }
  if (tid < 65536) {  // w_hh [1024][256] -> w_q[k][unit] float4 (i,f,g,o)
    int k = tid >> 8, t = tid & 255;
    float4 wv;
    wv.x = w_hh[(0 * 256 + t) * 256 + k];
    wv.y = w_hh[(1 * 256 + t) * 256 + k];
    wv.z = w_hh[(2 * 256 + t) * 256 + k];
    wv.w = w_hh[(3 * 256 + t) * 256 + k];
    *(float4*)&w_q[tid * 4] = wv;
  }
  if (tid < 1024) {  // gathered bias
    int u = tid >> 2, gate = tid & 3;
    biasg[tid] = b_ih[gate * 256 + u] + b_hh[gate * 256 + u];
  }
  if (tid < 81920) {  // w2 [64co][256ci][5] -> w2t [ci][dk][co]
    int ci = tid / 320, r = tid % 320, dk = r >> 6, co = r & 63;
    w2t[tid] = w2[(co * 256 + ci) * 5 + dk];
  }
  if (tid < 49152) {  // w3 [256co][64ci][3] -> w3t [ci][dk][co]
    int ci = tid / 768, r = tid % 768, dk = r >> 8, co = r & 255;
    w3t[tid] = w3[(co * 64 + ci) * 3 + dk];
  }
  if (tid < 4096) {  // w4 [16co][256ci] -> w4t [ci][co]
    int ci = tid >> 4, co = tid & 15;
    w4t[tid] = w4[co * 256 + ci];
  }
  if (tid < 65536) {  // fc1_w [128][512] -> fc1_wt [512][128]
    int k = tid >> 7, j = tid & 127;
    fc1_wt[tid] = fc1_w[j * 512 + k];
  }
  if (tid < 4096) {  // fc2_w [32][128] -> fc2_wt [128][32]
    int k = tid >> 5, j = tid & 31;
    fc2_wt[tid] = fc2_w[j * 128 + k];
  }
  if (tid < 64) {  // fc3_w [2][32] -> fc3_wt [32][2]
    int k = tid >> 1, j = tid & 1;
    fc3_wt[tid] = fc3_w[j * 32 + k];
  }
}

// ---------------------------------------------------------------------------
// gates GEMM via MFMA fp16x2 split (register-prefetch double buffer)
// ---------------------------------------------------------------------------
__global__ __launch_bounds__(256, 2) void gemm_gates_mfma(
    const _Float16* __restrict__ xs, const _Float16* __restrict__ wihs,
    const float* __restrict__ biasg, float* __restrict__ gates, int l0, int cmode) {
  __shared__ _Float16 Asp[2][128][APAD];
  __shared__ _Float16 Bsp[2][128][APAD];
  int tid = threadIdx.x;
  int gid = blockIdx.x;
  int mt = (gid & 7) + ((gid >> 6) << 3), nt = (gid >> 3) & 7;
  int m0 = mt << 7, n0 = nt << 7;
  int lane = tid & 63, w = tid >> 6;
  int wm = (w & 1) * 64, wn = (w >> 1) * 64;
  int r32 = lane & 31, hw8 = (lane >> 5) * 8;
  int g8 = (tid & 7) << 3;
  f16acc acc[2][2];
#pragma unroll
  for (int mm = 0; mm < 2; mm++)
#pragma unroll
    for (int nn = 0; nn < 2; nn++) acc[mm][nn] = (f16acc)(0.f);

  size_t abase[8], bbase[8];
#pragma unroll
  for (int i = 0; i < 8; i++) {
    int p = i >> 2, row = (i & 3) * 32 + (tid >> 3);
    int m = m0 + row;
    int xrow = cmode ? (((m >> 4) << 7) + l0 + (m & 15)) : m;
    abase[i] = (size_t)p * XSP + (size_t)xrow * 768 + g8;
    bbase[i] = (size_t)p * 786432 + (size_t)(n0 + row) * 768 + g8;
  }
  h8 ra[8], rb[8];
#pragma unroll
  for (int i = 0; i < 8; i++) {
    ra[i] = *(const h8*)&xs[abase[i]];
    rb[i] = *(const h8*)&wihs[bbase[i]];
  }

  for (int kc = 0; kc < 12; kc++) {
    if (kc) __syncthreads();
#pragma unroll
    for (int i = 0; i < 8; i++) {
      int p = i >> 2, row = (i & 3) * 32 + (tid >> 3);
      *(h8*)&Asp[p][row][g8] = ra[i];
      *(h8*)&Bsp[p][row][g8] = rb[i];
    }
    __syncthreads();
    if (kc < 11) {
      int k0 = (kc + 1) * 64;
#pragma unroll
      for (int i = 0; i < 8; i++) {
        ra[i] = *(const h8*)&xs[abase[i] + k0];
        rb[i] = *(const h8*)&wihs[bbase[i] + k0];
      }
    }
#pragma unroll
    for (int ks = 0; ks < 4; ks++) {
      int k = ks * 16 + hw8;
      h8 ah[2], al[2], bh[2], bl[2];
      ah[0] = *(const h8*)&Asp[0][wm + r32][k];
      ah[1] = *(const h8*)&Asp[0][wm + r32 + 32][k];
      al[0] = *(const h8*)&Asp[1][wm + r32][k];
      al[1] = *(const h8*)&Asp[1][wm + r32 + 32][k];
      bh[0] = *(const h8*)&Bsp[0][wn + r32][k];
      bh[1] = *(const h8*)&Bsp[0][wn + r32 + 32][k];
      bl[0] = *(const h8*)&Bsp[1][wn + r32][k];
      bl[1] = *(const h8*)&Bsp[1][wn + r32 + 32][k];
#pragma unroll
      for (int mm = 0; mm < 2; mm++)
#pragma unroll
        for (int nn = 0; nn < 2; nn++) {
          acc[mm][nn] = __builtin_amdgcn_mfma_f32_32x32x16_f16(ah[mm], bh[nn], acc[mm][nn], 0, 0, 0);
          acc[mm][nn] = __builtin_amdgcn_mfma_f32_32x32x16_f16(ah[mm], bl[nn], acc[mm][nn], 0, 0, 0);
          acc[mm][nn] = __builtin_amdgcn_mfma_f32_32x32x16_f16(al[mm], bh[nn], acc[mm][nn], 0, 0, 0);
        }
    }
  }
#pragma unroll
  for (int mm = 0; mm < 2; mm++)
#pragma unroll
    for (int nn = 0; nn < 2; nn++) {
      int n = n0 + wn + nn * 32 + r32;
      float bb = biasg[n];
#pragma unroll
      for (int reg = 0; reg < 16; reg++) {
        int row = (reg & 3) + 8 * (reg >> 2) + (hw8 >> 1);
        int m = m0 + wm + mm * 32 + row;
        gates[(size_t)m * 1024 + n] = acc[mm][nn][reg] * (1.f / 64.f) + bb;
      }
    }
}

// ---------------------------------------------------------------------------
// LSTM full recurrence, one launch. 128 blocks x 1024 threads (16 waves =
// 4 waves/SIMD on the active CUs). Block owns 4 batch rows. 4-way k-split:
// quarter q sums k in [64q, 64q+64) for all 4 rows; LDS ps reduce; thread
// (q,t) finalizes (row q, unit t). h kept transposed hl4f[k][r] so the 4
// per-row h values per k are ONE broadcast ds_read_b128. f4 vector math ->
// v_pk_fma_f32. w_q stream prefetched 8 deep.
// ---------------------------------------------------------------------------
__global__ __launch_bounds__(1024) void lstm_full(
    const float* __restrict__ gates, const float* __restrict__ w_q,
    float* __restrict__ z) {
  __shared__ __align__(16) float hl4f[256 * 4];      // [unit k][row]
  __shared__ __align__(16) float ps[4][4][256][4];   // [quarter][row][unit][gate]
  int tid = threadIdx.x;
  int t = tid & 255, q = tid >> 8;   // q = k-quarter AND the row this thread finalizes
  int r0 = blockIdx.x * 4;
  const f4* wq4 = (const f4*)w_q;
  float c = 0.f, hs = 0.f;
  hl4f[t * 4 + q] = 0.f;
  __syncthreads();
  int kb = q << 6;
  for (int lc = 0; lc < 128; lc++) {
    f4 a0 = (f4)(0.f), a1 = (f4)(0.f), a2 = (f4)(0.f), a3 = (f4)(0.f);
    f4 wbuf[8];
#pragma unroll
    for (int u = 0; u < 8; u++) wbuf[u] = wq4[(size_t)(kb + u) * 256 + t];
#pragma unroll 8
    for (int k = 0; k < 64; k++) {
      f4 wv = wbuf[k & 7];
      f4 hv = *(const f4*)&hl4f[(kb + k) * 4];   // broadcast read (all lanes same addr)
      if (k < 56) wbuf[k & 7] = wq4[(size_t)(kb + k + 8) * 256 + t];
      a0 += wv * hv[0];
      a1 += wv * hv[1];
      a2 += wv * hv[2];
      a3 += wv * hv[3];
    }
    *(f4*)&ps[q][0][t][0] = a0;
    *(f4*)&ps[q][1][t][0] = a1;
    *(f4*)&ps[q][2][t][0] = a2;
    *(f4*)&ps[q][3][t][0] = a3;
    __syncthreads();
    f4 s = *(const f4*)&ps[0][q][t][0];
    s += *(const f4*)&ps[1][q][t][0];
    s += *(const f4*)&ps[2][q][t][0];
    s += *(const f4*)&ps[3][q][t][0];
    float4 g4 = *(const float4*)&gates[((size_t)(r0 + q) * 128 + lc) * 1024 + t * 4];
    float gi = s[0] + g4.x;
    float gf = s[1] + g4.y;
    float gg = s[2] + g4.z;
    float go = s[3] + g4.w;
    float iv = fsig(gi), fv = fsig(gf), gv = ftanh(gg), ov = fsig(go);
    c = fv * c + iv * gv;
    float hv = ov * ftanh(c);
    hs += hv;
    hl4f[t * 4 + q] = hv;
    __syncthreads();
  }
  z[(size_t)(r0 + q) * 512 + t] = hs * (1.f / 128.f);
}

// ---------------------------------------------------------------------------
// LSTM chunked fallback (16 steps per launch) — used only if ws too small
// ---------------------------------------------------------------------------
__global__ __launch_bounds__(512) void lstm_chunk(
    const float* __restrict__ gates, const float* __restrict__ w_q,
    float* __restrict__ h_state, float* __restrict__ c_state, float* __restrict__ hsum,
    float* __restrict__ z, int first, int last, int gB, int l0f) {
  __shared__ float hl[4][256];
  __shared__ __align__(16) float ps[4][256][4];
  int tid = threadIdx.x;
  int t = tid & 255, half = tid >> 8;
  int r0 = blockIdx.x * 4;
  int rown = half * 2, rother = 2 - rown;
  float c2[2], hs2[2];
#pragma unroll
  for (int rr = 0; rr < 2; rr++) {
    int r = rown + rr;
    float hv;
    if (first) { hv = 0.f; c2[rr] = 0.f; hs2[rr] = 0.f; }
    else {
      hv = h_state[(r0 + r) * 256 + t];
      c2[rr] = c_state[(r0 + r) * 256 + t];
      hs2[rr] = hsum[(r0 + r) * 256 + t];
    }
    hl[r][t] = hv;
  }
  __syncthreads();
  int kb = half << 7;
  for (int lc = 0; lc < TCHUNK; lc++) {
    float4 a[4];
#pragma unroll
    for (int r = 0; r < 4; r++) a[r] = make_float4(0.f, 0.f, 0.f, 0.f);
#pragma unroll 4
    for (int k = 0; k < 128; k++) {
      float4 wv = *(const float4*)&w_q[(size_t)(kb + k) * 1024 + t * 4];
#pragma unroll
      for (int r = 0; r < 4; r++) {
        float hv = hl[r][kb + k];
        a[r].x += hv * wv.x; a[r].y += hv * wv.y;
        a[r].z += hv * wv.z; a[r].w += hv * wv.w;
      }
    }
#pragma unroll
    for (int rr = 0; rr < 2; rr++)
      *(float4*)&ps[rother + rr][t][0] = a[rother + rr];
    __syncthreads();
    float hnew[2];
#pragma unroll
    for (int rr = 0; rr < 2; rr++) {
      int r = rown + rr;
      float4 p = *(const float4*)&ps[r][t][0];
      float4 g4 = *(const float4*)&gates[((size_t)(r0 + r) * gB + l0f + lc) * 1024 + t * 4];
      float gi = a[r].x + p.x + g4.x;
      float gf = a[r].y + p.y + g4.y;
      float gg = a[r].z + p.z + g4.z;
      float go = a[r].w + p.w + g4.w;
      float iv = fsig(gi), fv = fsig(gf), gv = ftanh(gg), ov = fsig(go);
      c2[rr] = fv * c2[rr] + iv * gv;
      float hv = ov * ftanh(c2[rr]);
      hs2[rr] += hv;
      hnew[rr] = hv;
    }
#pragma unroll
    for (int rr = 0; rr < 2; rr++) hl[rown + rr][t] = hnew[rr];
    __syncthreads();
  }
#pragma unroll
  for (int rr = 0; rr < 2; rr++) {
    int r = rown + rr;
    h_state[(r0 + r) * 256 + t] = hl[r][t];
    c_state[(r0 + r) * 256 + t] = c2[rr];
    hsum[(r0 + r) * 256 + t] = hs2[rr];
    if (last) z[(r0 + r) * 512 + t] = hs2[rr] * (1.f / 128.f);
  }
}

// ---------------------------------------------------------------------------
// conv1 v3 via MFMA fp16x2: co=64/block, ci-chunk=32, B staged for ALL 7 dk
// ---------------------------------------------------------------------------
__global__ __launch_bounds__(256, 2) void conv1_mfma(
    const _Float16* __restrict__ xs, const _Float16* __restrict__ w1s,
    const float* __restrict__ b1, float* __restrict__ out1) {
  __shared__ _Float16 Asp[2][134][36];
  __shared__ _Float16 Bsp[2][64][228];
  int tid = threadIdx.x;
  int b = blockIdx.y;
  int co0 = blockIdx.x << 6;
  int lane = tid & 63, w = tid >> 6;
  int wm = (w & 1) * 64, wn = (w >> 1) * 32;
  int r32 = lane & 31, hw8 = (lane >> 5) * 8;
  f16acc acc[2];
  acc[0] = (f16acc)(0.f);
  acc[1] = (f16acc)(0.f);

  for (int cc = 0; cc < 24; cc++) {
    int ci0 = cc * 32;
    if (cc) __syncthreads();
    for (int f = tid; f < 1072; f += 256) {
      int p = f >= 536;
      int r = f - p * 536;
      int row = r >> 2, g = (r & 3) << 3;
      int l = row - 3;
      h8 v = (h8)(_Float16)0.f;
      if (l >= 0 && l < 128)
        v = *(const h8*)&xs[(size_t)p * XSP + ((size_t)b * 128 + l) * 768 + ci0 + g];
      *(h8*)&Asp[p][row][g] = v;
    }
    for (int f = tid; f < 3584; f += 256) {
      int p = f >= 1792;
      int r = f - p * 1792;
      int co = r / 28, gg = r - co * 28;
      int k = gg << 3;
      int dk = k >> 5, ci = k & 31;
      *(h8*)&Bsp[p][co][k] =
          *(const h8*)&w1s[(size_t)p * 1376256 + ((size_t)dk * 256 + co0 + co) * 768 + ci0 + ci];
    }
    __syncthreads();
#pragma unroll
    for (int ks = 0; ks < 14; ks++) {
      int dk = ks >> 1;
      int cib = ((ks & 1) << 4) + hw8;
      int kb = ks * 16 + hw8;
      h8 ah[2], al[2], bh, bl;
      ah[0] = *(const h8*)&Asp[0][wm + r32 + dk][cib];
      ah[1] = *(const h8*)&Asp[0][wm + 32 + r32 + dk][cib];
      al[0] = *(const h8*)&Asp[1][wm + r32 + dk][cib];
      al[1] = *(const h8*)&Asp[1][wm + 32 + r32 + dk][cib];
      bh = *(const h8*)&Bsp[0][wn + r32][kb];
      bl = *(const h8*)&Bsp[1][wn + r32][kb];
#pragma unroll
      for (int mm = 0; mm < 2; mm++) {
        acc[mm] = __builtin_amdgcn_mfma_f32_32x32x16_f16(ah[mm], bh, acc[mm], 0, 0, 0);
        acc[mm] = __builtin_amdgcn_mfma_f32_32x32x16_f16(ah[mm], bl, acc[mm], 0, 0, 0);
        acc[mm] = __builtin_amdgcn_mfma_f32_32x32x16_f16(al[mm], bh, acc[mm], 0, 0, 0);
      }
    }
  }
  int co = co0 + wn + r32;
  float bb = b1[co];
  size_t obase = ((size_t)b * 256 + co) * 64;
#pragma unroll
  for (int mm = 0; mm < 2; mm++) {
#pragma unroll
    for (int i = 0; i < 8; i++) {
      int rb = ((i & 1) << 1) + ((i >> 1) << 3) + (hw8 >> 1);
      float v = fmaxf(acc[mm][2 * i], acc[mm][2 * i + 1]) * (1.f / 64.f) + bb;
      out1[obase + ((wm + mm * 32 + rb) >> 1)] = fmaxf(v, 0.f);
    }
  }
}

// ---------------------------------------------------------------------------
// conv2 (256->64, K=5, pad2) + pool2 + relu -> out2 [512][64][32]
// ---------------------------------------------------------------------------
__global__ __launch_bounds__(256) void conv2_kernel(
    const float* __restrict__ out1, const float* __restrict__ w2t,
    const float* __restrict__ b2, float* __restrict__ out2) {
  __shared__ float X2[32 * 68];
  __shared__ __align__(16) float W2[32 * 5 * 64];
  int tid = threadIdx.x;
  int b = blockIdx.x;
  int co = tid & 63, pg = tid >> 6;
  float acc[16] = {};
  for (int c0 = 0; c0 < 256; c0 += 32) {
    for (int f = tid; f < 512; f += 256) {
      int ci = f >> 4, q = (f & 15) << 2;
      float4 v = *(const float4*)&out1[(b * 256 + c0 + ci) * 64 + q];
      X2[ci * 68 + 2 + q + 0] = v.x; X2[ci * 68 + 2 + q + 1] = v.y;
      X2[ci * 68 + 2 + q + 2] = v.z; X2[ci * 68 + 2 + q + 3] = v.w;
    }
    if (tid < 32) { X2[tid * 68] = 0.f; X2[tid * 68 + 1] = 0.f; X2[tid * 68 + 66] = 0.f; X2[tid * 68 + 67] = 0.f; }
    for (int f = tid; f < 2560; f += 256)
      *(float4*)&W2[f * 4] = *(const float4*)&w2t[c0 * 320 + f * 4];
    __syncthreads();
    for (int ci = 0; ci < 32; ci++) {
      float xv[20];
#pragma unroll
      for (int u = 0; u < 20; u++) xv[u] = X2[ci * 68 + pg * 16 + u];
#pragma unroll
      for (int dk = 0; dk < 5; dk++) {
        float w = W2[(ci * 5 + dk) * 64 + co];
#pragma unroll
        for (int i = 0; i < 16; i++) acc[i] += xv[i + dk] * w;
      }
    }
    __syncthreads();
  }
  float bb = b2[co];
#pragma unroll
  for (int p = 0; p < 8; p++) {
    float v = fmaxf(acc[2 * p], acc[2 * p + 1]) + bb;
    out2[(b * 64 + co) * 32 + pg * 8 + p] = fmaxf(v, 0.f);
  }
}

// ---------------------------------------------------------------------------
// conv3 (64->256, K=3, pad1) + pool2 + relu -> out3 [512][256][16]
// ---------------------------------------------------------------------------
__global__ __launch_bounds__(256) void conv3_kernel(
    const float* __restrict__ out2, const float* __restrict__ w3t,
    const float* __restrict__ b3, float* __restrict__ out3) {
  __shared__ float X3[64 * 34];
  __shared__ __align__(16) float W3[16 * 3 * 256];
  int tid = threadIdx.x;
  int b = blockIdx.x;
  float acc[32] = {};
  for (int f = tid; f < 512; f += 256) {
    int ci = f >> 3, q = (f & 7) << 2;
    float4 v = *(const float4*)&out2[(b * 64 + ci) * 32 + q];
    X3[ci * 34 + 1 + q + 0] = v.x; X3[ci * 34 + 1 + q + 1] = v.y;
    X3[ci * 34 + 1 + q + 2] = v.z; X3[ci * 34 + 1 + q + 3] = v.w;
  }
  if (tid < 64) { X3[tid * 34] = 0.f; X3[tid * 34 + 33] = 0.f; }
  __syncthreads();
  for (int c0 = 0; c0 < 64; c0 += 16) {
    for (int f = tid; f < 3072; f += 256)
      *(float4*)&W3[f * 4] = *(const float4*)&w3t[c0 * 768 + f * 4];
    __syncthreads();
    for (int ci = 0; ci < 16; ci++) {
      float xv[34];
#pragma unroll
      for (int u = 0; u < 34; u++) xv[u] = X3[(c0 + ci) * 34 + u];
#pragma unroll
      for (int dk = 0; dk < 3; dk++) {
        float w = W3[(ci * 3 + dk) * 256 + tid];
#pragma unroll
        for (int i = 0; i < 32; i++) acc[i] += xv[i + dk] * w;
      }
    }
    __syncthreads();
  }
  float bb = b3[tid];
#pragma unroll
  for (int p = 0; p < 16; p++) {
    float v = fmaxf(acc[2 * p], acc[2 * p + 1]) + bb;
    out3[(b * 256 + tid) * 16 + p] = fmaxf(v, 0.f);
  }
}

// ---------------------------------------------------------------------------
// conv4 (256->16, K=1) + relu -> z[:, 256:512]
// ---------------------------------------------------------------------------
__global__ __launch_bounds__(256) void conv4_kernel(
    const float* __restrict__ out3, const float* __restrict__ w4t,
    const float* __restrict__ b4, float* __restrict__ z) {
  __shared__ __align__(16) float X4[256 * 16];
  __shared__ __align__(16) float W4[256 * 16];
  int tid = threadIdx.x;
  int b = blockIdx.x;
  for (int f = tid; f < 1024; f += 256) {
    *(float4*)&X4[f * 4] = *(const float4*)&out3[b * 4096 + f * 4];
    *(float4*)&W4[f * 4] = *(const float4*)&w4t[f * 4];
  }
  __syncthreads();
  int co = tid >> 4, l = tid & 15;
  float acc = 0.f;
#pragma unroll 8
  for (int ci = 0; ci < 256; ci++) acc += X4[ci * 16 + l] * W4[ci * 16 + co];
  z[b * 512 + 256 + tid] = fmaxf(acc + b4[co], 0.f);
}

// ---------------------------------------------------------------------------
// MLP head
// ---------------------------------------------------------------------------
__global__ __launch_bounds__(128) void head_kernel(
    const float* __restrict__ z,
    const float* __restrict__ fc1_wt, const float* __restrict__ fc1_b,
    const float* __restrict__ fc2_wt, const float* __restrict__ fc2_b,
    const float* __restrict__ fc3_wt, const float* __restrict__ fc3_b,
    float* __restrict__ out) {
  __shared__ __align__(16) float zs[512];
  __shared__ float h1[128];
  __shared__ float h2[32];
  int tid = threadIdx.x;
  int b = blockIdx.x;
  *(float4*)&zs[tid * 4] = *(const float4*)&z[b * 512 + tid * 4];
  __syncthreads();
  float acc = 0.f;
#pragma unroll 8
  for (int k = 0; k < 512; k++) acc += zs[k] * fc1_wt[k * 128 + tid];
  h1[tid] = fmaxf(acc + fc1_b[tid], 0.f);
  __syncthreads();
  if (tid < 32) {
    float a2 = 0.f;
#pragma unroll 8
    for (int k = 0; k < 128; k++) a2 += h1[k] * fc2_wt[k * 32 + tid];
    h2[tid] = fmaxf(a2 + fc2_b[tid], 0.f);
  }
  __syncthreads();
  if (tid < 2) {
    float a3 = 0.f;
#pragma unroll
    for (int k = 0; k < 32; k++) a3 += h2[k] * fc3_wt[k * 2 + tid];
    out[b * 2 + tid] = fmaxf(a3 + fc3_b[tid], 0.f);
  }
}

// ---------------------------------------------------------------------------
extern "C" void kernel_launch(void* const* d_in, const int* in_sizes, int n_in,
                              void* d_out, int out_size, void* d_ws, size_t ws_size,
                              hipStream_t stream) {
  const float* x     = (const float*)d_in[0];
  const float* w_ih  = (const float*)d_in[1];
  const float* w_hh  = (const float*)d_in[2];
  const float* b_ih  = (const float*)d_in[3];
  const float* b_hh  = (const float*)d_in[4];
  const float* w1    = (const float*)d_in[5];
  const float* b1    = (const float*)d_in[6];
  const float* w2    = (const float*)d_in[7];
  const float* b2    = (const float*)d_in[8];
  const float* w3    = (const float*)d_in[9];
  const float* b3    = (const float*)d_in[10];
  const float* w4    = (const float*)d_in[11];
  const float* b4    = (const float*)d_in[12];
  const float* fc1_w = (const float*)d_in[13];
  const float* fc1_b = (const float*)d_in[14];
  const float* fc2_w = (const float*)d_in[15];
  const float* fc2_b = (const float*)d_in[16];
  const float* fc3_w = (const float*)d_in[17];
  const float* fc3_b = (const float*)d_in[18];
  float* out = (float*)d_out;

  const size_t gfull = (size_t)65536 * 1024, gchunk = (size_t)8192 * 1024;
  const size_t xsf = (size_t)XSP;  // xs = 2*XSP halfs = XSP floats
  const size_t rest = 262144 + 1024 + 3 * 131072 + 262144 + 8388608 + 1048576 +
                      2097152 + 81920 + 49152 + 4096 + 65536 + 4096 + 64 + 786432;
  int full = (ws_size >= (gfull + xsf + rest) * 4) ? 1 : 0;
  size_t gsz = full ? gfull : gchunk;

  float* W = (float*)d_ws;
  size_t o = 0;
  float* gates  = W + o; o += gsz;
  float* w_q    = W + o; o += 262144;
  float* biasg  = W + o; o += 1024;
  float* h_st   = W + o; o += 131072;
  float* c_st   = W + o; o += 131072;
  float* hsum   = W + o; o += 131072;
  float* z      = W + o; o += 262144;
  float* out1   = W + o; o += (size_t)512 * 256 * 64;
  float* out2   = W + o; o += (size_t)512 * 64 * 32;
  float* out3   = W + o; o += (size_t)512 * 256 * 16;
  float* w2t    = W + o; o += 81920;
  float* w3t    = W + o; o += 49152;
  float* w4t    = W + o; o += 4096;
  float* fc1_wt = W + o; o += 65536;
  float* fc2_wt = W + o; o += 4096;
  float* fc3_wt = W + o; o += 64;
  _Float16* wihs = (_Float16*)(W + o); o += 786432;  // 2x1024x768 halfs
  _Float16* xs   = (_Float16*)(W + o); o += xsf;     // 2x65536x768 halfs
  // w1 fp16 split (5.5 MB) aliases out3 (8.4 MB): conv1 reads it strictly
  // before conv3 writes out3 (stream order), so the overlap is safe.
  _Float16* w1s = (_Float16*)out3;
  (void)in_sizes; (void)n_in; (void)out_size;

  xsplit_kernel<<<24576, 256, 0, stream>>>(x, xs);
  prep_kernel<<<5376, 256, 0, stream>>>(w_ih, w_hh, b_ih, b_hh, w1, w2, w3, w4,
                                        fc1_w, fc2_w, fc3_w,
                                        w_q, biasg, w1s, wihs, w2t, w3t, w4t,
                                        fc1_wt, fc2_wt, fc3_wt);
  if (full) {
    gemm_gates_mfma<<<4096, 256, 0, stream>>>(xs, wihs, biasg, gates, 0, 0);
    lstm_full<<<128, 1024, 0, stream>>>(gates, w_q, z);
  } else {
    for (int c = 0; c < NCHUNK; c++) {
      gemm_gates_mfma<<<512, 256, 0, stream>>>(xs, wihs, biasg, gates, c * TCHUNK, 1);
      lstm_chunk<<<128, 512, 0, stream>>>(gates, w_q, h_st, c_st, hsum, z,
                                          c == 0, c == NCHUNK - 1, 16, 0);
    }
  }
  conv1_mfma<<<dim3(4, 512), 256, 0, stream>>>(xs, w1s, b1, out1);
  conv2_kernel<<<512, 256, 0, stream>>>(out1, w2t, b2, out2);
  conv3_kernel<<<512, 256, 0, stream>>>(out2, w3t, b3, out3);
  conv4_kernel<<<512, 256, 0, stream>>>(out3, w4t, b4, z);
  head_kernel<<<512, 128, 0, stream>>>(z, fc1_wt, fc1_b, fc2_wt, fc2_b, fc3_wt, fc3_b, out);
}

// Round 7
// 3106.838 us; speedup vs baseline: 22.6858x; 22.6858x over previous
//
#include <hip/hip_runtime.h>

// Model dims
#define BB 512
#define LL 128
#define HH 768
#define LHID 256
#define TCHUNK 16
#define NCHUNK 8

typedef _Float16 h8 __attribute__((ext_vector_type(8)));
typedef _Float16 h4 __attribute__((ext_vector_type(4)));
typedef float f16acc __attribute__((ext_vector_type(16)));

#define APAD 72        // LDS row stride in halfs (gemm)
#define XSP 50331648   // 65536*768, one part of split x

__device__ __forceinline__ float fsig(float x) { return 1.f / (1.f + __expf(-x)); }
__device__ __forceinline__ float ftanh(float x) { return 1.f - 2.f / (__expf(2.f * x) + 1.f); }

// ---------------------------------------------------------------------------
// xsplit: x fp32 -> fp16 hi/lo parts
// ---------------------------------------------------------------------------
__global__ __launch_bounds__(256) void xsplit_kernel(
    const float* __restrict__ x, _Float16* __restrict__ xs) {
  size_t e = ((size_t)blockIdx.x * 256 + threadIdx.x) * 8;
  float4 a = *(const float4*)&x[e];
  float4 b = *(const float4*)&x[e + 4];
  h8 hi, lo;
  hi[0] = (_Float16)a.x; lo[0] = (_Float16)(a.x - (float)hi[0]);
  hi[1] = (_Float16)a.y; lo[1] = (_Float16)(a.y - (float)hi[1]);
  hi[2] = (_Float16)a.z; lo[2] = (_Float16)(a.z - (float)hi[2]);
  hi[3] = (_Float16)a.w; lo[3] = (_Float16)(a.w - (float)hi[3]);
  hi[4] = (_Float16)b.x; lo[4] = (_Float16)(b.x - (float)hi[4]);
  hi[5] = (_Float16)b.y; lo[5] = (_Float16)(b.y - (float)hi[5]);
  hi[6] = (_Float16)b.z; lo[6] = (_Float16)(b.z - (float)hi[6]);
  hi[7] = (_Float16)b.w; lo[7] = (_Float16)(b.w - (float)hi[7]);
  *(h8*)&xs[e] = hi;
  *(h8*)&xs[XSP + e] = lo;
}

// ---------------------------------------------------------------------------
// prep: weight transposes / fp16 splits / LSTM bias fuse
// ---------------------------------------------------------------------------
__global__ __launch_bounds__(256) void prep_kernel(
    const float* __restrict__ w_ih, const float* __restrict__ w_hh,
    const float* __restrict__ b_ih, const float* __restrict__ b_hh,
    const float* __restrict__ w1, const float* __restrict__ w2, const float* __restrict__ w3,
    const float* __restrict__ w4,
    const float* __restrict__ fc1_w, const float* __restrict__ fc2_w, const float* __restrict__ fc3_w,
    float* __restrict__ w_q, float* __restrict__ biasg,
    _Float16* __restrict__ w1s, _Float16* __restrict__ wihs,
    float* __restrict__ w2t, float* __restrict__ w3t, float* __restrict__ w4t,
    float* __restrict__ fc1_wt, float* __restrict__ fc2_wt, float* __restrict__ fc3_wt) {
  int tid = blockIdx.x * 256 + threadIdx.x;  // grid = 5376*256 = 1376256
  if (tid < 1376256) {  // w1 [co][ci][dk] -> fp16 split hi/lo, layout [dk][co][ci], x64
    int dk = tid / 196608, r = tid % 196608, co = r / 768, ci = r % 768;
    float v = w1[((size_t)co * 768 + ci) * 7 + dk] * 64.f;
    _Float16 h = (_Float16)v;
    w1s[tid] = h;
    w1s[1376256 + tid] = (_Float16)(v - (float)h);
  }
  if (tid < 786432) {  // w_ih -> fp16 split hi/lo, x64, GATHERED rows n' = u*4+gate
    int np = tid / 768, k = tid % 768;
    int u = np >> 2, gate = np & 3;
    float v = w_ih[(size_t)(gate * 256 + u) * 768 + k] * 64.f;
    _Float16 h = (_Float16)v;
    wihs[tid] = h;
    wihs[786432 + tid] = (_Float16)(v - (float)h);
  }
  if (tid < 65536) {  // w_hh [1024][256] -> w_q[k][unit] float4 (i,f,g,o)
    int k = tid >> 8, t = tid & 255;
    float4 wv;
    wv.x = w_hh[(0 * 256 + t) * 256 + k];
    wv.y = w_hh[(1 * 256 + t) * 256 + k];
    wv.z = w_hh[(2 * 256 + t) * 256 + k];
    wv.w = w_hh[(3 * 256 + t) * 256 + k];
    *(float4*)&w_q[tid * 4] = wv;
  }
  if (tid < 1024) {  // gathered bias
    int u = tid >> 2, gate = tid & 3;
    biasg[tid] = b_ih[gate * 256 + u] + b_hh[gate * 256 + u];
  }
  if (tid < 81920) {  // w2 [64co][256ci][5] -> w2t [ci][dk][co]
    int ci = tid / 320, r = tid % 320, dk = r >> 6, co = r & 63;
    w2t[tid] = w2[(co * 256 + ci) * 5 + dk];
  }
  if (tid < 49152) {  // w3 [256co][64ci][3] -> w3t [ci][dk][co]
    int ci = tid / 768, r = tid % 768, dk = r >> 8, co = r & 255;
    w3t[tid] = w3[(co * 64 + ci) * 3 + dk];
  }
  if (tid < 4096) {  // w4 [16co][256ci] -> w4t [ci][co]
    int ci = tid >> 4, co = tid & 15;
    w4t[tid] = w4[co * 256 + ci];
  }
  if (tid < 65536) {  // fc1_w [128][512] -> fc1_wt [512][128]
    int k = tid >> 7, j = tid & 127;
    fc1_wt[tid] = fc1_w[j * 512 + k];
  }
  if (tid < 4096) {  // fc2_w [32][128] -> fc2_wt [128][32]
    int k = tid >> 5, j = tid & 31;
    fc2_wt[tid] = fc2_w[j * 128 + k];
  }
  if (tid < 64) {  // fc3_w [2][32] -> fc3_wt [32][2]
    int k = tid >> 1, j = tid & 1;
    fc3_wt[tid] = fc3_w[j * 32 + k];
  }
}

// ---------------------------------------------------------------------------
// gates GEMM via MFMA fp16x2 split (register-prefetch double buffer)
// ---------------------------------------------------------------------------
__global__ __launch_bounds__(256, 2) void gemm_gates_mfma(
    const _Float16* __restrict__ xs, const _Float16* __restrict__ wihs,
    const float* __restrict__ biasg, float* __restrict__ gates, int l0, int cmode) {
  __shared__ _Float16 Asp[2][128][APAD];
  __shared__ _Float16 Bsp[2][128][APAD];
  int tid = threadIdx.x;
  int gid = blockIdx.x;
  int mt = (gid & 7) + ((gid >> 6) << 3), nt = (gid >> 3) & 7;
  int m0 = mt << 7, n0 = nt << 7;
  int lane = tid & 63, w = tid >> 6;
  int wm = (w & 1) * 64, wn = (w >> 1) * 64;
  int r32 = lane & 31, hw8 = (lane >> 5) * 8;
  int g8 = (tid & 7) << 3;
  f16acc acc[2][2];
#pragma unroll
  for (int mm = 0; mm < 2; mm++)
#pragma unroll
    for (int nn = 0; nn < 2; nn++) acc[mm][nn] = (f16acc)(0.f);

  size_t abase[8], bbase[8];
#pragma unroll
  for (int i = 0; i < 8; i++) {
    int p = i >> 2, row = (i & 3) * 32 + (tid >> 3);
    int m = m0 + row;
    int xrow = cmode ? (((m >> 4) << 7) + l0 + (m & 15)) : m;
    abase[i] = (size_t)p * XSP + (size_t)xrow * 768 + g8;
    bbase[i] = (size_t)p * 786432 + (size_t)(n0 + row) * 768 + g8;
  }
  h8 ra[8], rb[8];
#pragma unroll
  for (int i = 0; i < 8; i++) {
    ra[i] = *(const h8*)&xs[abase[i]];
    rb[i] = *(const h8*)&wihs[bbase[i]];
  }

  for (int kc = 0; kc < 12; kc++) {
    if (kc) __syncthreads();
#pragma unroll
    for (int i = 0; i < 8; i++) {
      int p = i >> 2, row = (i & 3) * 32 + (tid >> 3);
      *(h8*)&Asp[p][row][g8] = ra[i];
      *(h8*)&Bsp[p][row][g8] = rb[i];
    }
    __syncthreads();
    if (kc < 11) {
      int k0 = (kc + 1) * 64;
#pragma unroll
      for (int i = 0; i < 8; i++) {
        ra[i] = *(const h8*)&xs[abase[i] + k0];
        rb[i] = *(const h8*)&wihs[bbase[i] + k0];
      }
    }
#pragma unroll
    for (int ks = 0; ks < 4; ks++) {
      int k = ks * 16 + hw8;
      h8 ah[2], al[2], bh[2], bl[2];
      ah[0] = *(const h8*)&Asp[0][wm + r32][k];
      ah[1] = *(const h8*)&Asp[0][wm + r32 + 32][k];
      al[0] = *(const h8*)&Asp[1][wm + r32][k];
      al[1] = *(const h8*)&Asp[1][wm + r32 + 32][k];
      bh[0] = *(const h8*)&Bsp[0][wn + r32][k];
      bh[1] = *(const h8*)&Bsp[0][wn + r32 + 32][k];
      bl[0] = *(const h8*)&Bsp[1][wn + r32][k];
      bl[1] = *(const h8*)&Bsp[1][wn + r32 + 32][k];
#pragma unroll
      for (int mm = 0; mm < 2; mm++)
#pragma unroll
        for (int nn = 0; nn < 2; nn++) {
          acc[mm][nn] = __builtin_amdgcn_mfma_f32_32x32x16_f16(ah[mm], bh[nn], acc[mm][nn], 0, 0, 0);
          acc[mm][nn] = __builtin_amdgcn_mfma_f32_32x32x16_f16(ah[mm], bl[nn], acc[mm][nn], 0, 0, 0);
          acc[mm][nn] = __builtin_amdgcn_mfma_f32_32x32x16_f16(al[mm], bh[nn], acc[mm][nn], 0, 0, 0);
        }
    }
  }
#pragma unroll
  for (int mm = 0; mm < 2; mm++)
#pragma unroll
    for (int nn = 0; nn < 2; nn++) {
      int n = n0 + wn + nn * 32 + r32;
      float bb = biasg[n];
#pragma unroll
      for (int reg = 0; reg < 16; reg++) {
        int row = (reg & 3) + 8 * (reg >> 2) + (hw8 >> 1);
        int m = m0 + wm + mm * 32 + row;
        gates[(size_t)m * 1024 + n] = acc[mm][nn][reg] * (1.f / 64.f) + bb;
      }
    }
}

// ---------------------------------------------------------------------------
// LSTM full recurrence, one launch. 128 blocks x 1024 threads (16 waves =
// 4 waves/SIMD on the 128 active CUs — 2x round-5 TLP). Block owns 4 batch
// rows. 4-way k-split: quarter q sums k in [64q,64q+64) for all 4 rows
// (per-block w_q stream stays 1 MB/step -> L2-resident, 16 GB total).
// Plain rolled loads + scalar FMA body (round-5 proven codegen, VGPR ~44;
// NO register prefetch ring — round 6 proved it spills to scratch).
// LDS ps reduce; thread (q,t) finalizes (row q, unit t).
// ---------------------------------------------------------------------------
__global__ __launch_bounds__(1024) void lstm_full(
    const float* __restrict__ gates, const float* __restrict__ w_q,
    float* __restrict__ z) {
  __shared__ float hl[4][256];
  __shared__ __align__(16) float ps[4][4][256][4];  // [kq][row][unit][gate]
  int tid = threadIdx.x;
  int t = tid & 255, q = tid >> 8;  // q = k-quarter AND the row this thread finalizes
  int r0 = blockIdx.x * 4;
  float c = 0.f, hs = 0.f;
  hl[q][t] = 0.f;
  __syncthreads();
  int kb = q << 6;
  for (int lc = 0; lc < 128; lc++) {
    float4 a[4];
#pragma unroll
    for (int r = 0; r < 4; r++) a[r] = make_float4(0.f, 0.f, 0.f, 0.f);
#pragma unroll 4
    for (int k = 0; k < 64; k++) {
      float4 wv = *(const float4*)&w_q[(size_t)(kb + k) * 1024 + t * 4];
#pragma unroll
      for (int r = 0; r < 4; r++) {
        float hv = hl[r][kb + k];  // broadcast (all lanes same address)
        a[r].x += hv * wv.x; a[r].y += hv * wv.y;
        a[r].z += hv * wv.z; a[r].w += hv * wv.w;
      }
    }
#pragma unroll
    for (int r = 0; r < 4; r++)
      *(float4*)&ps[q][r][t][0] = a[r];
    __syncthreads();
    float4 p0 = *(const float4*)&ps[0][q][t][0];
    float4 p1 = *(const float4*)&ps[1][q][t][0];
    float4 p2 = *(const float4*)&ps[2][q][t][0];
    float4 p3 = *(const float4*)&ps[3][q][t][0];
    float4 g4 = *(const float4*)&gates[((size_t)(r0 + q) * 128 + lc) * 1024 + t * 4];
    float gi = p0.x + p1.x + p2.x + p3.x + g4.x;
    float gf = p0.y + p1.y + p2.y + p3.y + g4.y;
    float gg = p0.z + p1.z + p2.z + p3.z + g4.z;
    float go = p0.w + p1.w + p2.w + p3.w + g4.w;
    float iv = fsig(gi), fv = fsig(gf), gv = ftanh(gg), ov = fsig(go);
    c = fv * c + iv * gv;
    float hv = ov * ftanh(c);
    hs += hv;
    hl[q][t] = hv;
    __syncthreads();
  }
  z[(size_t)(r0 + q) * 512 + t] = hs * (1.f / 128.f);
}

// ---------------------------------------------------------------------------
// LSTM chunked fallback (16 steps per launch) — used only if ws too small
// ---------------------------------------------------------------------------
__global__ __launch_bounds__(512) void lstm_chunk(
    const float* __restrict__ gates, const float* __restrict__ w_q,
    float* __restrict__ h_state, float* __restrict__ c_state, float* __restrict__ hsum,
    float* __restrict__ z, int first, int last, int gB, int l0f) {
  __shared__ float hl[4][256];
  __shared__ __align__(16) float ps[4][256][4];
  int tid = threadIdx.x;
  int t = tid & 255, half = tid >> 8;
  int r0 = blockIdx.x * 4;
  int rown = half * 2, rother = 2 - rown;
  float c2[2], hs2[2];
#pragma unroll
  for (int rr = 0; rr < 2; rr++) {
    int r = rown + rr;
    float hv;
    if (first) { hv = 0.f; c2[rr] = 0.f; hs2[rr] = 0.f; }
    else {
      hv = h_state[(r0 + r) * 256 + t];
      c2[rr] = c_state[(r0 + r) * 256 + t];
      hs2[rr] = hsum[(r0 + r) * 256 + t];
    }
    hl[r][t] = hv;
  }
  __syncthreads();
  int kb = half << 7;
  for (int lc = 0; lc < TCHUNK; lc++) {
    float4 a[4];
#pragma unroll
    for (int r = 0; r < 4; r++) a[r] = make_float4(0.f, 0.f, 0.f, 0.f);
#pragma unroll 4
    for (int k = 0; k < 128; k++) {
      float4 wv = *(const float4*)&w_q[(size_t)(kb + k) * 1024 + t * 4];
#pragma unroll
      for (int r = 0; r < 4; r++) {
        float hv = hl[r][kb + k];
        a[r].x += hv * wv.x; a[r].y += hv * wv.y;
        a[r].z += hv * wv.z; a[r].w += hv * wv.w;
      }
    }
#pragma unroll
    for (int rr = 0; rr < 2; rr++)
      *(float4*)&ps[rother + rr][t][0] = a[rother + rr];
    __syncthreads();
    float hnew[2];
#pragma unroll
    for (int rr = 0; rr < 2; rr++) {
      int r = rown + rr;
      float4 p = *(const float4*)&ps[r][t][0];
      float4 g4 = *(const float4*)&gates[((size_t)(r0 + r) * gB + l0f + lc) * 1024 + t * 4];
      float gi = a[r].x + p.x + g4.x;
      float gf = a[r].y + p.y + g4.y;
      float gg = a[r].z + p.z + g4.z;
      float go = a[r].w + p.w + g4.w;
      float iv = fsig(gi), fv = fsig(gf), gv = ftanh(gg), ov = fsig(go);
      c2[rr] = fv * c2[rr] + iv * gv;
      float hv = ov * ftanh(c2[rr]);
      hs2[rr] += hv;
      hnew[rr] = hv;
    }
#pragma unroll
    for (int rr = 0; rr < 2; rr++) hl[rown + rr][t] = hnew[rr];
    __syncthreads();
  }
#pragma unroll
  for (int rr = 0; rr < 2; rr++) {
    int r = rown + rr;
    h_state[(r0 + r) * 256 + t] = hl[r][t];
    c_state[(r0 + r) * 256 + t] = c2[rr];
    hsum[(r0 + r) * 256 + t] = hs2[rr];
    if (last) z[(r0 + r) * 512 + t] = hs2[rr] * (1.f / 128.f);
  }
}

// ---------------------------------------------------------------------------
// conv1 v3 via MFMA fp16x2: co=64/block, ci-chunk=32, B staged for ALL 7 dk
// ---------------------------------------------------------------------------
__global__ __launch_bounds__(256, 2) void conv1_mfma(
    const _Float16* __restrict__ xs, const _Float16* __restrict__ w1s,
    const float* __restrict__ b1, float* __restrict__ out1) {
  __shared__ _Float16 Asp[2][134][36];
  __shared__ _Float16 Bsp[2][64][228];
  int tid = threadIdx.x;
  int b = blockIdx.y;
  int co0 = blockIdx.x << 6;
  int lane = tid & 63, w = tid >> 6;
  int wm = (w & 1) * 64, wn = (w >> 1) * 32;
  int r32 = lane & 31, hw8 = (lane >> 5) * 8;
  f16acc acc[2];
  acc[0] = (f16acc)(0.f);
  acc[1] = (f16acc)(0.f);

  for (int cc = 0; cc < 24; cc++) {
    int ci0 = cc * 32;
    if (cc) __syncthreads();
    for (int f = tid; f < 1072; f += 256) {
      int p = f >= 536;
      int r = f - p * 536;
      int row = r >> 2, g = (r & 3) << 3;
      int l = row - 3;
      h8 v = (h8)(_Float16)0.f;
      if (l >= 0 && l < 128)
        v = *(const h8*)&xs[(size_t)p * XSP + ((size_t)b * 128 + l) * 768 + ci0 + g];
      *(h8*)&Asp[p][row][g] = v;
    }
    for (int f = tid; f < 3584; f += 256) {
      int p = f >= 1792;
      int r = f - p * 1792;
      int co = r / 28, gg = r - co * 28;
      int k = gg << 3;
      int dk = k >> 5, ci = k & 31;
      *(h8*)&Bsp[p][co][k] =
          *(const h8*)&w1s[(size_t)p * 1376256 + ((size_t)dk * 256 + co0 + co) * 768 + ci0 + ci];
    }
    __syncthreads();
#pragma unroll
    for (int ks = 0; ks < 14; ks++) {
      int dk = ks >> 1;
      int cib = ((ks & 1) << 4) + hw8;
      int kb = ks * 16 + hw8;
      h8 ah[2], al[2], bh, bl;
      ah[0] = *(const h8*)&Asp[0][wm + r32 + dk][cib];
      ah[1] = *(const h8*)&Asp[0][wm + 32 + r32 + dk][cib];
      al[0] = *(const h8*)&Asp[1][wm + r32 + dk][cib];
      al[1] = *(const h8*)&Asp[1][wm + 32 + r32 + dk][cib];
      bh = *(const h8*)&Bsp[0][wn + r32][kb];
      bl = *(const h8*)&Bsp[1][wn + r32][kb];
#pragma unroll
      for (int mm = 0; mm < 2; mm++) {
        acc[mm] = __builtin_amdgcn_mfma_f32_32x32x16_f16(ah[mm], bh, acc[mm], 0, 0, 0);
        acc[mm] = __builtin_amdgcn_mfma_f32_32x32x16_f16(ah[mm], bl, acc[mm], 0, 0, 0);
        acc[mm] = __builtin_amdgcn_mfma_f32_32x32x16_f16(al[mm], bh, acc[mm], 0, 0, 0);
      }
    }
  }
  int co = co0 + wn + r32;
  float bb = b1[co];
  size_t obase = ((size_t)b * 256 + co) * 64;
#pragma unroll
  for (int mm = 0; mm < 2; mm++) {
#pragma unroll
    for (int i = 0; i < 8; i++) {
      int rb = ((i & 1) << 1) + ((i >> 1) << 3) + (hw8 >> 1);
      float v = fmaxf(acc[mm][2 * i], acc[mm][2 * i + 1]) * (1.f / 64.f) + bb;
      out1[obase + ((wm + mm * 32 + rb) >> 1)] = fmaxf(v, 0.f);
    }
  }
}

// ---------------------------------------------------------------------------
// conv2 (256->64, K=5, pad2) + pool2 + relu -> out2 [512][64][32]
// ---------------------------------------------------------------------------
__global__ __launch_bounds__(256) void conv2_kernel(
    const float* __restrict__ out1, const float* __restrict__ w2t,
    const float* __restrict__ b2, float* __restrict__ out2) {
  __shared__ float X2[32 * 68];
  __shared__ __align__(16) float W2[32 * 5 * 64];
  int tid = threadIdx.x;
  int b = blockIdx.x;
  int co = tid & 63, pg = tid >> 6;
  float acc[16] = {};
  for (int c0 = 0; c0 < 256; c0 += 32) {
    for (int f = tid; f < 512; f += 256) {
      int ci = f >> 4, q = (f & 15) << 2;
      float4 v = *(const float4*)&out1[(b * 256 + c0 + ci) * 64 + q];
      X2[ci * 68 + 2 + q + 0] = v.x; X2[ci * 68 + 2 + q + 1] = v.y;
      X2[ci * 68 + 2 + q + 2] = v.z; X2[ci * 68 + 2 + q + 3] = v.w;
    }
    if (tid < 32) { X2[tid * 68] = 0.f; X2[tid * 68 + 1] = 0.f; X2[tid * 68 + 66] = 0.f; X2[tid * 68 + 67] = 0.f; }
    for (int f = tid; f < 2560; f += 256)
      *(float4*)&W2[f * 4] = *(const float4*)&w2t[c0 * 320 + f * 4];
    __syncthreads();
    for (int ci = 0; ci < 32; ci++) {
      float xv[20];
#pragma unroll
      for (int u = 0; u < 20; u++) xv[u] = X2[ci * 68 + pg * 16 + u];
#pragma unroll
      for (int dk = 0; dk < 5; dk++) {
        float w = W2[(ci * 5 + dk) * 64 + co];
#pragma unroll
        for (int i = 0; i < 16; i++) acc[i] += xv[i + dk] * w;
      }
    }
    __syncthreads();
  }
  float bb = b2[co];
#pragma unroll
  for (int p = 0; p < 8; p++) {
    float v = fmaxf(acc[2 * p], acc[2 * p + 1]) + bb;
    out2[(b * 64 + co) * 32 + pg * 8 + p] = fmaxf(v, 0.f);
  }
}

// ---------------------------------------------------------------------------
// conv3 (64->256, K=3, pad1) + pool2 + relu -> out3 [512][256][16]
// ---------------------------------------------------------------------------
__global__ __launch_bounds__(256) void conv3_kernel(
    const float* __restrict__ out2, const float* __restrict__ w3t,
    const float* __restrict__ b3, float* __restrict__ out3) {
  __shared__ float X3[64 * 34];
  __shared__ __align__(16) float W3[16 * 3 * 256];
  int tid = threadIdx.x;
  int b = blockIdx.x;
  float acc[32] = {};
  for (int f = tid; f < 512; f += 256) {
    int ci = f >> 3, q = (f & 7) << 2;
    float4 v = *(const float4*)&out2[(b * 64 + ci) * 32 + q];
    X3[ci * 34 + 1 + q + 0] = v.x; X3[ci * 34 + 1 + q + 1] = v.y;
    X3[ci * 34 + 1 + q + 2] = v.z; X3[ci * 34 + 1 + q + 3] = v.w;
  }
  if (tid < 64) { X3[tid * 34] = 0.f; X3[tid * 34 + 33] = 0.f; }
  __syncthreads();
  for (int c0 = 0; c0 < 64; c0 += 16) {
    for (int f = tid; f < 3072; f += 256)
      *(float4*)&W3[f * 4] = *(const float4*)&w3t[c0 * 768 + f * 4];
    __syncthreads();
    for (int ci = 0; ci < 16; ci++) {
      float xv[34];
#pragma unroll
      for (int u = 0; u < 34; u++) xv[u] = X3[(c0 + ci) * 34 + u];
#pragma unroll
      for (int dk = 0; dk < 3; dk++) {
        float w = W3[(ci * 3 + dk) * 256 + tid];
#pragma unroll
        for (int i = 0; i < 32; i++) acc[i] += xv[i + dk] * w;
      }
    }
    __syncthreads();
  }
  float bb = b3[tid];
#pragma unroll
  for (int p = 0; p < 16; p++) {
    float v = fmaxf(acc[2 * p], acc[2 * p + 1]) + bb;
    out3[(b * 256 + tid) * 16 + p] = fmaxf(v, 0.f);
  }
}

// ---------------------------------------------------------------------------
// conv4 (256->16, K=1) + relu -> z[:, 256:512]
// ---------------------------------------------------------------------------
__global__ __launch_bounds__(256) void conv4_kernel(
    const float* __restrict__ out3, const float* __restrict__ w4t,
    const float* __restrict__ b4, float* __restrict__ z) {
  __shared__ __align__(16) float X4[256 * 16];
  __shared__ __align__(16) float W4[256 * 16];
  int tid = threadIdx.x;
  int b = blockIdx.x;
  for (int f = tid; f < 1024; f += 256) {
    *(float4*)&X4[f * 4] = *(const float4*)&out3[b * 4096 + f * 4];
    *(float4*)&W4[f * 4] = *(const float4*)&w4t[f * 4];
  }
  __syncthreads();
  int co = tid >> 4, l = tid & 15;
  float acc = 0.f;
#pragma unroll 8
  for (int ci = 0; ci < 256; ci++) acc += X4[ci * 16 + l] * W4[ci * 16 + co];
  z[b * 512 + 256 + tid] = fmaxf(acc + b4[co], 0.f);
}

// ---------------------------------------------------------------------------
// MLP head
// ---------------------------------------------------------------------------
__global__ __launch_bounds__(128) void head_kernel(
    const float* __restrict__ z,
    const float* __restrict__ fc1_wt, const float* __restrict__ fc1_b,
    const float* __restrict__ fc2_wt, const float* __restrict__ fc2_b,
    const float* __restrict__ fc3_wt, const float* __restrict__ fc3_b,
    float* __restrict__ out) {
  __shared__ __align__(16) float zs[512];
  __shared__ float h1[128];
  __shared__ float h2[32];
  int tid = threadIdx.x;
  int b = blockIdx.x;
  *(float4*)&zs[tid * 4] = *(const float4*)&z[b * 512 + tid * 4];
  __syncthreads();
  float acc = 0.f;
#pragma unroll 8
  for (int k = 0; k < 512; k++) acc += zs[k] * fc1_wt[k * 128 + tid];
  h1[tid] = fmaxf(acc + fc1_b[tid], 0.f);
  __syncthreads();
  if (tid < 32) {
    float a2 = 0.f;
#pragma unroll 8
    for (int k = 0; k < 128; k++) a2 += h1[k] * fc2_wt[k * 32 + tid];
    h2[tid] = fmaxf(a2 + fc2_b[tid], 0.f);
  }
  __syncthreads();
  if (tid < 2) {
    float a3 = 0.f;
#pragma unroll
    for (int k = 0; k < 32; k++) a3 += h2[k] * fc3_wt[k * 2 + tid];
    out[b * 2 + tid] = fmaxf(a3 + fc3_b[tid], 0.f);
  }
}

// ---------------------------------------------------------------------------
extern "C" void kernel_launch(void* const* d_in, const int* in_sizes, int n_in,
                              void* d_out, int out_size, void* d_ws, size_t ws_size,
                              hipStream_t stream) {
  const float* x     = (const float*)d_in[0];
  const float* w_ih  = (const float*)d_in[1];
  const float* w_hh  = (const float*)d_in[2];
  const float* b_ih  = (const float*)d_in[3];
  const float* b_hh  = (const float*)d_in[4];
  const float* w1    = (const float*)d_in[5];
  const float* b1    = (const float*)d_in[6];
  const float* w2    = (const float*)d_in[7];
  const float* b2    = (const float*)d_in[8];
  const float* w3    = (const float*)d_in[9];
  const float* b3    = (const float*)d_in[10];
  const float* w4    = (const float*)d_in[11];
  const float* b4    = (const float*)d_in[12];
  const float* fc1_w = (const float*)d_in[13];
  const float* fc1_b = (const float*)d_in[14];
  const float* fc2_w = (const float*)d_in[15];
  const float* fc2_b = (const float*)d_in[16];
  const float* fc3_w = (const float*)d_in[17];
  const float* fc3_b = (const float*)d_in[18];
  float* out = (float*)d_out;

  const size_t gfull = (size_t)65536 * 1024, gchunk = (size_t)8192 * 1024;
  const size_t xsf = (size_t)XSP;  // xs = 2*XSP halfs = XSP floats
  const size_t rest = 262144 + 1024 + 3 * 131072 + 262144 + 8388608 + 1048576 +
                      2097152 + 81920 + 49152 + 4096 + 65536 + 4096 + 64 + 786432;
  int full = (ws_size >= (gfull + xsf + rest) * 4) ? 1 : 0;
  size_t gsz = full ? gfull : gchunk;

  float* W = (float*)d_ws;
  size_t o = 0;
  float* gates  = W + o; o += gsz;
  float* w_q    = W + o; o += 262144;
  float* biasg  = W + o; o += 1024;
  float* h_st   = W + o; o += 131072;
  float* c_st   = W + o; o += 131072;
  float* hsum   = W + o; o += 131072;
  float* z      = W + o; o += 262144;
  float* out1   = W + o; o += (size_t)512 * 256 * 64;
  float* out2   = W + o; o += (size_t)512 * 64 * 32;
  float* out3   = W + o; o += (size_t)512 * 256 * 16;
  float* w2t    = W + o; o += 81920;
  float* w3t    = W + o; o += 49152;
  float* w4t    = W + o; o += 4096;
  float* fc1_wt = W + o; o += 65536;
  float* fc2_wt = W + o; o += 4096;
  float* fc3_wt = W + o; o += 64;
  _Float16* wihs = (_Float16*)(W + o); o += 786432;  // 2x1024x768 halfs
  _Float16* xs   = (_Float16*)(W + o); o += xsf;     // 2x65536x768 halfs
  // w1 fp16 split (5.5 MB) aliases out3 (8.4 MB): conv1 reads it strictly
  // before conv3 writes out3 (stream order), so the overlap is safe.
  _Float16* w1s = (_Float16*)out3;
  (void)in_sizes; (void)n_in; (void)out_size;

  xsplit_kernel<<<24576, 256, 0, stream>>>(x, xs);
  prep_kernel<<<5376, 256, 0, stream>>>(w_ih, w_hh, b_ih, b_hh, w1, w2, w3, w4,
                                        fc1_w, fc2_w, fc3_w,
                                        w_q, biasg, w1s, wihs, w2t, w3t, w4t,
                                        fc1_wt, fc2_wt, fc3_wt);
  if (full) {
    gemm_gates_mfma<<<4096, 256, 0, stream>>>(xs, wihs, biasg, gates, 0, 0);
    lstm_full<<<128, 1024, 0, stream>>>(gates, w_q, z);
  } else {
    for (int c = 0; c < NCHUNK; c++) {
      gemm_gates_mfma<<<512, 256, 0, stream>>>(xs, wihs, biasg, gates, c * TCHUNK, 1);
      lstm_chunk<<<128, 512, 0, stream>>>(gates, w_q, h_st, c_st, hsum, z,
                                          c == 0, c == NCHUNK - 1, 16, 0);
    }
  }
  conv1_mfma<<<dim3(4, 512), 256, 0, stream>>>(xs, w1s, b1, out1);
  conv2_kernel<<<512, 256, 0, stream>>>(out1, w2t, b2, out2);
  conv3_kernel<<<512, 256, 0, stream>>>(out2, w3t, b3, out3);
  conv4_kernel<<<512, 256, 0, stream>>>(out3, w4t, b4, z);
  head_kernel<<<512, 128, 0, stream>>>(z, fc1_wt, fc1_b, fc2_wt, fc2_b, fc3_wt, fc3_b, out);
}

// Round 8
// 2604.108 us; speedup vs baseline: 27.0653x; 1.1931x over previous
//
#include <hip/hip_runtime.h>

// Model dims
#define BB 512
#define LL 128
#define HH 768
#define LHID 256
#define TCHUNK 16
#define NCHUNK 8

typedef _Float16 h8 __attribute__((ext_vector_type(8)));
typedef _Float16 h4 __attribute__((ext_vector_type(4)));
typedef float f16acc __attribute__((ext_vector_type(16)));

#define APAD 72        // LDS row stride in halfs (gemm)
#define XSP 50331648   // 65536*768, one part of split x

__device__ __forceinline__ float fsig(float x) { return 1.f / (1.f + __expf(-x)); }
__device__ __forceinline__ float ftanh(float x) { return 1.f - 2.f / (__expf(2.f * x) + 1.f); }

// ---------------------------------------------------------------------------
// xsplit: x fp32 -> fp16 hi/lo parts
// ---------------------------------------------------------------------------
__global__ __launch_bounds__(256) void xsplit_kernel(
    const float* __restrict__ x, _Float16* __restrict__ xs) {
  size_t e = ((size_t)blockIdx.x * 256 + threadIdx.x) * 8;
  float4 a = *(const float4*)&x[e];
  float4 b = *(const float4*)&x[e + 4];
  h8 hi, lo;
  hi[0] = (_Float16)a.x; lo[0] = (_Float16)(a.x - (float)hi[0]);
  hi[1] = (_Float16)a.y; lo[1] = (_Float16)(a.y - (float)hi[1]);
  hi[2] = (_Float16)a.z; lo[2] = (_Float16)(a.z - (float)hi[2]);
  hi[3] = (_Float16)a.w; lo[3] = (_Float16)(a.w - (float)hi[3]);
  hi[4] = (_Float16)b.x; lo[4] = (_Float16)(b.x - (float)hi[4]);
  hi[5] = (_Float16)b.y; lo[5] = (_Float16)(b.y - (float)hi[5]);
  hi[6] = (_Float16)b.z; lo[6] = (_Float16)(b.z - (float)hi[6]);
  hi[7] = (_Float16)b.w; lo[7] = (_Float16)(b.w - (float)hi[7]);
  *(h8*)&xs[e] = hi;
  *(h8*)&xs[XSP + e] = lo;
}

// ---------------------------------------------------------------------------
// prep: weight transposes / fp16 splits / LSTM bias fuse
// ---------------------------------------------------------------------------
__global__ __launch_bounds__(256) void prep_kernel(
    const float* __restrict__ w_ih, const float* __restrict__ w_hh,
    const float* __restrict__ b_ih, const float* __restrict__ b_hh,
    const float* __restrict__ w1, const float* __restrict__ w2, const float* __restrict__ w3,
    const float* __restrict__ w4,
    const float* __restrict__ fc1_w, const float* __restrict__ fc2_w, const float* __restrict__ fc3_w,
    float* __restrict__ w_q, float* __restrict__ biasg,
    _Float16* __restrict__ w1s, _Float16* __restrict__ wihs,
    float* __restrict__ w2t, float* __restrict__ w3t, float* __restrict__ w4t,
    float* __restrict__ fc1_wt, float* __restrict__ fc2_wt, float* __restrict__ fc3_wt) {
  int tid = blockIdx.x * 256 + threadIdx.x;  // grid = 5376*256 = 1376256
  if (tid < 1376256) {  // w1 [co][ci][dk] -> fp16 split hi/lo, layout [dk][co][ci], x64
    int dk = tid / 196608, r = tid % 196608, co = r / 768, ci = r % 768;
    float v = w1[((size_t)co * 768 + ci) * 7 + dk] * 64.f;
    _Float16 h = (_Float16)v;
    w1s[tid] = h;
    w1s[1376256 + tid] = (_Float16)(v - (float)h);
  }
  if (tid < 786432) {  // w_ih -> fp16 split hi/lo, x64, GATHERED rows n' = u*4+gate
    int np = tid / 768, k = tid % 768;
    int u = np >> 2, gate = np & 3;
    float v = w_ih[(size_t)(gate * 256 + u) * 768 + k] * 64.f;
    _Float16 h = (_Float16)v;
    wihs[tid] = h;
    wihs[786432 + tid] = (_Float16)(v - (float)h);
  }
  if (tid < 65536) {  // w_hh [1024][256] -> w_q[k][unit] float4 (i,f,g,o)
    int k = tid >> 8, t = tid & 255;
    float4 wv;
    wv.x = w_hh[(0 * 256 + t) * 256 + k];
    wv.y = w_hh[(1 * 256 + t) * 256 + k];
    wv.z = w_hh[(2 * 256 + t) * 256 + k];
    wv.w = w_hh[(3 * 256 + t) * 256 + k];
    *(float4*)&w_q[tid * 4] = wv;
  }
  if (tid < 1024) {  // gathered bias
    int u = tid >> 2, gate = tid & 3;
    biasg[tid] = b_ih[gate * 256 + u] + b_hh[gate * 256 + u];
  }
  if (tid < 81920) {  // w2 [64co][256ci][5] -> w2t [ci][dk][co]
    int ci = tid / 320, r = tid % 320, dk = r >> 6, co = r & 63;
    w2t[tid] = w2[(co * 256 + ci) * 5 + dk];
  }
  if (tid < 49152) {  // w3 [256co][64ci][3] -> w3t [ci][dk][co]
    int ci = tid / 768, r = tid % 768, dk = r >> 8, co = r & 255;
    w3t[tid] = w3[(co * 64 + ci) * 3 + dk];
  }
  if (tid < 4096) {  // w4 [16co][256ci] -> w4t [ci][co]
    int ci = tid >> 4, co = tid & 15;
    w4t[tid] = w4[co * 256 + ci];
  }
  if (tid < 65536) {  // fc1_w [128][512] -> fc1_wt [512][128]
    int k = tid >> 7, j = tid & 127;
    fc1_wt[tid] = fc1_w[j * 512 + k];
  }
  if (tid < 4096) {  // fc2_w [32][128] -> fc2_wt [128][32]
    int k = tid >> 5, j = tid & 31;
    fc2_wt[tid] = fc2_w[j * 128 + k];
  }
  if (tid < 64) {  // fc3_w [2][32] -> fc3_wt [32][2]
    int k = tid >> 1, j = tid & 1;
    fc3_wt[tid] = fc3_w[j * 32 + k];
  }
}

// ---------------------------------------------------------------------------
// gates GEMM via MFMA fp16x2 split (register-prefetch double buffer)
// ---------------------------------------------------------------------------
__global__ __launch_bounds__(256, 2) void gemm_gates_mfma(
    const _Float16* __restrict__ xs, const _Float16* __restrict__ wihs,
    const float* __restrict__ biasg, float* __restrict__ gates, int l0, int cmode) {
  __shared__ _Float16 Asp[2][128][APAD];
  __shared__ _Float16 Bsp[2][128][APAD];
  int tid = threadIdx.x;
  int gid = blockIdx.x;
  int mt = (gid & 7) + ((gid >> 6) << 3), nt = (gid >> 3) & 7;
  int m0 = mt << 7, n0 = nt << 7;
  int lane = tid & 63, w = tid >> 6;
  int wm = (w & 1) * 64, wn = (w >> 1) * 64;
  int r32 = lane & 31, hw8 = (lane >> 5) * 8;
  int g8 = (tid & 7) << 3;
  f16acc acc[2][2];
#pragma unroll
  for (int mm = 0; mm < 2; mm++)
#pragma unroll
    for (int nn = 0; nn < 2; nn++) acc[mm][nn] = (f16acc)(0.f);

  size_t abase[8], bbase[8];
#pragma unroll
  for (int i = 0; i < 8; i++) {
    int p = i >> 2, row = (i & 3) * 32 + (tid >> 3);
    int m = m0 + row;
    int xrow = cmode ? (((m >> 4) << 7) + l0 + (m & 15)) : m;
    abase[i] = (size_t)p * XSP + (size_t)xrow * 768 + g8;
    bbase[i] = (size_t)p * 786432 + (size_t)(n0 + row) * 768 + g8;
  }
  h8 ra[8], rb[8];
#pragma unroll
  for (int i = 0; i < 8; i++) {
    ra[i] = *(const h8*)&xs[abase[i]];
    rb[i] = *(const h8*)&wihs[bbase[i]];
  }

  for (int kc = 0; kc < 12; kc++) {
    if (kc) __syncthreads();
#pragma unroll
    for (int i = 0; i < 8; i++) {
      int p = i >> 2, row = (i & 3) * 32 + (tid >> 3);
      *(h8*)&Asp[p][row][g8] = ra[i];
      *(h8*)&Bsp[p][row][g8] = rb[i];
    }
    __syncthreads();
    if (kc < 11) {
      int k0 = (kc + 1) * 64;
#pragma unroll
      for (int i = 0; i < 8; i++) {
        ra[i] = *(const h8*)&xs[abase[i] + k0];
        rb[i] = *(const h8*)&wihs[bbase[i] + k0];
      }
    }
#pragma unroll
    for (int ks = 0; ks < 4; ks++) {
      int k = ks * 16 + hw8;
      h8 ah[2], al[2], bh[2], bl[2];
      ah[0] = *(const h8*)&Asp[0][wm + r32][k];
      ah[1] = *(const h8*)&Asp[0][wm + r32 + 32][k];
      al[0] = *(const h8*)&Asp[1][wm + r32][k];
      al[1] = *(const h8*)&Asp[1][wm + r32 + 32][k];
      bh[0] = *(const h8*)&Bsp[0][wn + r32][k];
      bh[1] = *(const h8*)&Bsp[0][wn + r32 + 32][k];
      bl[0] = *(const h8*)&Bsp[1][wn + r32][k];
      bl[1] = *(const h8*)&Bsp[1][wn + r32 + 32][k];
#pragma unroll
      for (int mm = 0; mm < 2; mm++)
#pragma unroll
        for (int nn = 0; nn < 2; nn++) {
          acc[mm][nn] = __builtin_amdgcn_mfma_f32_32x32x16_f16(ah[mm], bh[nn], acc[mm][nn], 0, 0, 0);
          acc[mm][nn] = __builtin_amdgcn_mfma_f32_32x32x16_f16(ah[mm], bl[nn], acc[mm][nn], 0, 0, 0);
          acc[mm][nn] = __builtin_amdgcn_mfma_f32_32x32x16_f16(al[mm], bh[nn], acc[mm][nn], 0, 0, 0);
        }
    }
  }
#pragma unroll
  for (int mm = 0; mm < 2; mm++)
#pragma unroll
    for (int nn = 0; nn < 2; nn++) {
      int n = n0 + wn + nn * 32 + r32;
      float bb = biasg[n];
#pragma unroll
      for (int reg = 0; reg < 16; reg++) {
        int row = (reg & 3) + 8 * (reg >> 2) + (hw8 >> 1);
        int m = m0 + wm + mm * 32 + row;
        gates[(size_t)m * 1024 + n] = acc[mm][nn][reg] * (1.f / 64.f) + bb;
      }
    }
}

// ---------------------------------------------------------------------------
// LSTM full recurrence, one launch. 128 blocks x 1024 threads.
// LDS-pipe fix: h stored TRANSPOSED hT[unit][4 rows] so the 4 per-row h
// values at unit k are ONE broadcast ds_read_b128 (12 cyc) instead of
// 4x ds_read_b32 (23 cyc) — round-7 counters proved the LDS pipe is the
// step-time limiter (25.4K cyc/CU/step ~= measured 26.4K).
// NO register prefetch rings (round-6 scratch-demotion lesson).
// ---------------------------------------------------------------------------
__global__ __launch_bounds__(1024) void lstm_full(
    const float* __restrict__ gates, const float* __restrict__ w_q,
    float* __restrict__ z) {
  __shared__ __align__(16) float hT[256][4];        // [unit][row]
  __shared__ __align__(16) float ps[4][4][256][4];  // [kq][row][unit][gate]
  int tid = threadIdx.x;
  int t = tid & 255, q = tid >> 8;  // q = k-quarter AND the row this thread finalizes
  int r0 = blockIdx.x * 4;
  float c = 0.f, hs = 0.f;
  hT[t][q] = 0.f;
  __syncthreads();
  int kb = q << 6;
  for (int lc = 0; lc < 128; lc++) {
    float4 a[4];
#pragma unroll
    for (int r = 0; r < 4; r++) a[r] = make_float4(0.f, 0.f, 0.f, 0.f);
#pragma unroll 4
    for (int k = 0; k < 64; k++) {
      float4 wv = *(const float4*)&w_q[(size_t)(kb + k) * 1024 + t * 4];
      float4 hv = *(const float4*)&hT[kb + k][0];  // b128 broadcast
      a[0].x += hv.x * wv.x; a[0].y += hv.x * wv.y; a[0].z += hv.x * wv.z; a[0].w += hv.x * wv.w;
      a[1].x += hv.y * wv.x; a[1].y += hv.y * wv.y; a[1].z += hv.y * wv.z; a[1].w += hv.y * wv.w;
      a[2].x += hv.z * wv.x; a[2].y += hv.z * wv.y; a[2].z += hv.z * wv.z; a[2].w += hv.z * wv.w;
      a[3].x += hv.w * wv.x; a[3].y += hv.w * wv.y; a[3].z += hv.w * wv.z; a[3].w += hv.w * wv.w;
    }
#pragma unroll
    for (int r = 0; r < 4; r++)
      *(float4*)&ps[q][r][t][0] = a[r];
    __syncthreads();
    float4 p0 = *(const float4*)&ps[0][q][t][0];
    float4 p1 = *(const float4*)&ps[1][q][t][0];
    float4 p2 = *(const float4*)&ps[2][q][t][0];
    float4 p3 = *(const float4*)&ps[3][q][t][0];
    float4 g4 = *(const float4*)&gates[((size_t)(r0 + q) * 128 + lc) * 1024 + t * 4];
    float gi = p0.x + p1.x + p2.x + p3.x + g4.x;
    float gf = p0.y + p1.y + p2.y + p3.y + g4.y;
    float gg = p0.z + p1.z + p2.z + p3.z + g4.z;
    float go = p0.w + p1.w + p2.w + p3.w + g4.w;
    float iv = fsig(gi), fv = fsig(gf), gv = ftanh(gg), ov = fsig(go);
    c = fv * c + iv * gv;
    float hv = ov * ftanh(c);
    hs += hv;
    hT[t][q] = hv;
    __syncthreads();
  }
  z[(size_t)(r0 + q) * 512 + t] = hs * (1.f / 128.f);
}

// ---------------------------------------------------------------------------
// LSTM chunked fallback (16 steps per launch) — used only if ws too small
// ---------------------------------------------------------------------------
__global__ __launch_bounds__(512) void lstm_chunk(
    const float* __restrict__ gates, const float* __restrict__ w_q,
    float* __restrict__ h_state, float* __restrict__ c_state, float* __restrict__ hsum,
    float* __restrict__ z, int first, int last, int gB, int l0f) {
  __shared__ float hl[4][256];
  __shared__ __align__(16) float ps[4][256][4];
  int tid = threadIdx.x;
  int t = tid & 255, half = tid >> 8;
  int r0 = blockIdx.x * 4;
  int rown = half * 2, rother = 2 - rown;
  float c2[2], hs2[2];
#pragma unroll
  for (int rr = 0; rr < 2; rr++) {
    int r = rown + rr;
    float hv;
    if (first) { hv = 0.f; c2[rr] = 0.f; hs2[rr] = 0.f; }
    else {
      hv = h_state[(r0 + r) * 256 + t];
      c2[rr] = c_state[(r0 + r) * 256 + t];
      hs2[rr] = hsum[(r0 + r) * 256 + t];
    }
    hl[r][t] = hv;
  }
  __syncthreads();
  int kb = half << 7;
  for (int lc = 0; lc < TCHUNK; lc++) {
    float4 a[4];
#pragma unroll
    for (int r = 0; r < 4; r++) a[r] = make_float4(0.f, 0.f, 0.f, 0.f);
#pragma unroll 4
    for (int k = 0; k < 128; k++) {
      float4 wv = *(const float4*)&w_q[(size_t)(kb + k) * 1024 + t * 4];
#pragma unroll
      for (int r = 0; r < 4; r++) {
        float hv = hl[r][kb + k];
        a[r].x += hv * wv.x; a[r].y += hv * wv.y;
        a[r].z += hv * wv.z; a[r].w += hv * wv.w;
      }
    }
#pragma unroll
    for (int rr = 0; rr < 2; rr++)
      *(float4*)&ps[rother + rr][t][0] = a[rother + rr];
    __syncthreads();
    float hnew[2];
#pragma unroll
    for (int rr = 0; rr < 2; rr++) {
      int r = rown + rr;
      float4 p = *(const float4*)&ps[r][t][0];
      float4 g4 = *(const float4*)&gates[((size_t)(r0 + r) * gB + l0f + lc) * 1024 + t * 4];
      float gi = a[r].x + p.x + g4.x;
      float gf = a[r].y + p.y + g4.y;
      float gg = a[r].z + p.z + g4.z;
      float go = a[r].w + p.w + g4.w;
      float iv = fsig(gi), fv = fsig(gf), gv = ftanh(gg), ov = fsig(go);
      c2[rr] = fv * c2[rr] + iv * gv;
      float hv = ov * ftanh(c2[rr]);
      hs2[rr] += hv;
      hnew[rr] = hv;
    }
#pragma unroll
    for (int rr = 0; rr < 2; rr++) hl[rown + rr][t] = hnew[rr];
    __syncthreads();
  }
#pragma unroll
  for (int rr = 0; rr < 2; rr++) {
    int r = rown + rr;
    h_state[(r0 + r) * 256 + t] = hl[r][t];
    c_state[(r0 + r) * 256 + t] = c2[rr];
    hsum[(r0 + r) * 256 + t] = hs2[rr];
    if (last) z[(r0 + r) * 512 + t] = hs2[rr] * (1.f / 128.f);
  }
}

// ---------------------------------------------------------------------------
// conv1 v4 via MFMA fp16x2: co=64/block, ci-chunk=32, B staged for ALL 7 dk,
// register-prefetch double buffer (gemm round-4 pattern): halo rows of A are
// zeroed ONCE pre-loop, so per chunk each thread has exactly 4 unconditional
// A loads + 14 unconditional B loads — fully unrolled, no guarded register
// writes (no scratch demotion). Next chunk's loads fly under 84 MFMAs.
// ---------------------------------------------------------------------------
__global__ __launch_bounds__(256, 2) void conv1_mfma(
    const _Float16* __restrict__ xs, const _Float16* __restrict__ w1s,
    const float* __restrict__ b1, float* __restrict__ out1) {
  __shared__ _Float16 Asp[2][136][36];   // rows 3..130 = l 0..127; rows 0-2,131-135 zero halo
  __shared__ _Float16 Bsp[2][64][228];   // [p][co][k=dk*32+ci]
  int tid = threadIdx.x;
  int b = blockIdx.y;
  int co0 = blockIdx.x << 6;
  int lane = tid & 63, w = tid >> 6;
  int wm = (w & 1) * 64, wn = (w >> 1) * 32;
  int r32 = lane & 31, hw8 = (lane >> 5) * 8;
  f16acc acc[2];
  acc[0] = (f16acc)(0.f);
  acc[1] = (f16acc)(0.f);

  // zero the 8 halo rows once (2p x 8 rows x 4 h8 = 64 writes)
  if (tid < 64) {
    int p = tid >= 32;
    int r = tid & 31;
    int rr = r >> 2;                       // 0..7
    int row = (rr < 3) ? rr : (128 + rr);  // 0,1,2,131..135
    int g = (r & 3) << 3;
    *(h8*)&Asp[p][row][g] = (h8)(_Float16)0.f;
  }

  // per-thread staging addresses (chunk-invariant bases)
  size_t abase[4], bbase[14];
  int adst_row[4], adst_g[4], bdst_p[14], bdst_co[14], bdst_k[14];
#pragma unroll
  for (int i = 0; i < 4; i++) {
    int f = tid + 256 * i;        // 0..1023
    int p = f >> 9, r = f & 511;
    int l = r >> 2, g = (r & 3) << 3;
    adst_row[i] = 3 + l; adst_g[i] = g;
    abase[i] = (size_t)(f >> 9) * XSP + ((size_t)b * 128 + l) * 768 + g;
    (void)p;
  }
#pragma unroll
  for (int i = 0; i < 14; i++) {
    int f = tid + 256 * i;        // 0..3583
    int p = f >= 1792;
    int r = f - p * 1792;
    int co = r / 28, j = r - co * 28;
    int k = j << 3;
    int dk = k >> 5, ci = k & 31;
    bdst_p[i] = p; bdst_co[i] = co; bdst_k[i] = k;
    bbase[i] = (size_t)p * 1376256 + ((size_t)dk * 256 + co0 + co) * 768 + ci;
  }
  h8 ra[4], rb[14];
#pragma unroll
  for (int i = 0; i < 4; i++) ra[i] = *(const h8*)&xs[abase[i]];
#pragma unroll
  for (int i = 0; i < 14; i++) rb[i] = *(const h8*)&w1s[bbase[i]];

  for (int cc = 0; cc < 24; cc++) {
    if (cc) __syncthreads();
#pragma unroll
    for (int i = 0; i < 4; i++) {
      int f = tid + 256 * i;
      *(h8*)&Asp[f >> 9][adst_row[i]][adst_g[i]] = ra[i];
    }
#pragma unroll
    for (int i = 0; i < 14; i++)
      *(h8*)&Bsp[bdst_p[i]][bdst_co[i]][bdst_k[i]] = rb[i];
    __syncthreads();
    if (cc < 23) {
      int off = (cc + 1) * 32;
#pragma unroll
      for (int i = 0; i < 4; i++) ra[i] = *(const h8*)&xs[abase[i] + off];
#pragma unroll
      for (int i = 0; i < 14; i++) rb[i] = *(const h8*)&w1s[bbase[i] + off];
    }
#pragma unroll
    for (int ks = 0; ks < 14; ks++) {
      int dk = ks >> 1;
      int cib = ((ks & 1) << 4) + hw8;
      int kb = ks * 16 + hw8;
      h8 ah[2], al[2], bh, bl;
      ah[0] = *(const h8*)&Asp[0][wm + r32 + dk][cib];
      ah[1] = *(const h8*)&Asp[0][wm + 32 + r32 + dk][cib];
      al[0] = *(const h8*)&Asp[1][wm + r32 + dk][cib];
      al[1] = *(const h8*)&Asp[1][wm + 32 + r32 + dk][cib];
      bh = *(const h8*)&Bsp[0][wn + r32][kb];
      bl = *(const h8*)&Bsp[1][wn + r32][kb];
#pragma unroll
      for (int mm = 0; mm < 2; mm++) {
        acc[mm] = __builtin_amdgcn_mfma_f32_32x32x16_f16(ah[mm], bh, acc[mm], 0, 0, 0);
        acc[mm] = __builtin_amdgcn_mfma_f32_32x32x16_f16(ah[mm], bl, acc[mm], 0, 0, 0);
        acc[mm] = __builtin_amdgcn_mfma_f32_32x32x16_f16(al[mm], bh, acc[mm], 0, 0, 0);
      }
    }
  }
  int co = co0 + wn + r32;
  float bb = b1[co];
  size_t obase = ((size_t)b * 256 + co) * 64;
#pragma unroll
  for (int mm = 0; mm < 2; mm++) {
#pragma unroll
    for (int i = 0; i < 8; i++) {
      int rb2 = ((i & 1) << 1) + ((i >> 1) << 3) + (hw8 >> 1);
      float v = fmaxf(acc[mm][2 * i], acc[mm][2 * i + 1]) * (1.f / 64.f) + bb;
      out1[obase + ((wm + mm * 32 + rb2) >> 1)] = fmaxf(v, 0.f);
    }
  }
}

// ---------------------------------------------------------------------------
// conv2 (256->64, K=5, pad2) + pool2 + relu -> out2 [512][64][32]
// ---------------------------------------------------------------------------
__global__ __launch_bounds__(256) void conv2_kernel(
    const float* __restrict__ out1, const float* __restrict__ w2t,
    const float* __restrict__ b2, float* __restrict__ out2) {
  __shared__ float X2[32 * 68];
  __shared__ __align__(16) float W2[32 * 5 * 64];
  int tid = threadIdx.x;
  int b = blockIdx.x;
  int co = tid & 63, pg = tid >> 6;
  float acc[16] = {};
  for (int c0 = 0; c0 < 256; c0 += 32) {
    for (int f = tid; f < 512; f += 256) {
      int ci = f >> 4, q = (f & 15) << 2;
      float4 v = *(const float4*)&out1[(b * 256 + c0 + ci) * 64 + q];
      X2[ci * 68 + 2 + q + 0] = v.x; X2[ci * 68 + 2 + q + 1] = v.y;
      X2[ci * 68 + 2 + q + 2] = v.z; X2[ci * 68 + 2 + q + 3] = v.w;
    }
    if (tid < 32) { X2[tid * 68] = 0.f; X2[tid * 68 + 1] = 0.f; X2[tid * 68 + 66] = 0.f; X2[tid * 68 + 67] = 0.f; }
    for (int f = tid; f < 2560; f += 256)
      *(float4*)&W2[f * 4] = *(const float4*)&w2t[c0 * 320 + f * 4];
    __syncthreads();
    for (int ci = 0; ci < 32; ci++) {
      float xv[20];
#pragma unroll
      for (int u = 0; u < 20; u++) xv[u] = X2[ci * 68 + pg * 16 + u];
#pragma unroll
      for (int dk = 0; dk < 5; dk++) {
        float w = W2[(ci * 5 + dk) * 64 + co];
#pragma unroll
        for (int i = 0; i < 16; i++) acc[i] += xv[i + dk] * w;
      }
    }
    __syncthreads();
  }
  float bb = b2[co];
#pragma unroll
  for (int p = 0; p < 8; p++) {
    float v = fmaxf(acc[2 * p], acc[2 * p + 1]) + bb;
    out2[(b * 64 + co) * 32 + pg * 8 + p] = fmaxf(v, 0.f);
  }
}

// ---------------------------------------------------------------------------
// conv3 (64->256, K=3, pad1) + pool2 + relu -> out3 [512][256][16]
// ---------------------------------------------------------------------------
__global__ __launch_bounds__(256) void conv3_kernel(
    const float* __restrict__ out2, const float* __restrict__ w3t,
    const float* __restrict__ b3, float* __restrict__ out3) {
  __shared__ float X3[64 * 34];
  __shared__ __align__(16) float W3[16 * 3 * 256];
  int tid = threadIdx.x;
  int b = blockIdx.x;
  float acc[32] = {};
  for (int f = tid; f < 512; f += 256) {
    int ci = f >> 3, q = (f & 7) << 2;
    float4 v = *(const float4*)&out2[(b * 64 + ci) * 32 + q];
    X3[ci * 34 + 1 + q + 0] = v.x; X3[ci * 34 + 1 + q + 1] = v.y;
    X3[ci * 34 + 1 + q + 2] = v.z; X3[ci * 34 + 1 + q + 3] = v.w;
  }
  if (tid < 64) { X3[tid * 34] = 0.f; X3[tid * 34 + 33] = 0.f; }
  __syncthreads();
  for (int c0 = 0; c0 < 64; c0 += 16) {
    for (int f = tid; f < 3072; f += 256)
      *(float4*)&W3[f * 4] = *(const float4*)&w3t[c0 * 768 + f * 4];
    __syncthreads();
    for (int ci = 0; ci < 16; ci++) {
      float xv[34];
#pragma unroll
      for (int u = 0; u < 34; u++) xv[u] = X3[(c0 + ci) * 34 + u];
#pragma unroll
      for (int dk = 0; dk < 3; dk++) {
        float w = W3[(ci * 3 + dk) * 256 + tid];
#pragma unroll
        for (int i = 0; i < 32; i++) acc[i] += xv[i + dk] * w;
      }
    }
    __syncthreads();
  }
  float bb = b3[tid];
#pragma unroll
  for (int p = 0; p < 16; p++) {
    float v = fmaxf(acc[2 * p], acc[2 * p + 1]) + bb;
    out3[(b * 256 + tid) * 16 + p] = fmaxf(v, 0.f);
  }
}

// ---------------------------------------------------------------------------
// conv4 (256->16, K=1) + relu -> z[:, 256:512]
// ---------------------------------------------------------------------------
__global__ __launch_bounds__(256) void conv4_kernel(
    const float* __restrict__ out3, const float* __restrict__ w4t,
    const float* __restrict__ b4, float* __restrict__ z) {
  __shared__ __align__(16) float X4[256 * 16];
  __shared__ __align__(16) float W4[256 * 16];
  int tid = threadIdx.x;
  int b = blockIdx.x;
  for (int f = tid; f < 1024; f += 256) {
    *(float4*)&X4[f * 4] = *(const float4*)&out3[b * 4096 + f * 4];
    *(float4*)&W4[f * 4] = *(const float4*)&w4t[f * 4];
  }
  __syncthreads();
  int co = tid >> 4, l = tid & 15;
  float acc = 0.f;
#pragma unroll 8
  for (int ci = 0; ci < 256; ci++) acc += X4[ci * 16 + l] * W4[ci * 16 + co];
  z[b * 512 + 256 + tid] = fmaxf(acc + b4[co], 0.f);
}

// ---------------------------------------------------------------------------
// MLP head
// ---------------------------------------------------------------------------
__global__ __launch_bounds__(128) void head_kernel(
    const float* __restrict__ z,
    const float* __restrict__ fc1_wt, const float* __restrict__ fc1_b,
    const float* __restrict__ fc2_wt, const float* __restrict__ fc2_b,
    const float* __restrict__ fc3_wt, const float* __restrict__ fc3_b,
    float* __restrict__ out) {
  __shared__ __align__(16) float zs[512];
  __shared__ float h1[128];
  __shared__ float h2[32];
  int tid = threadIdx.x;
  int b = blockIdx.x;
  *(float4*)&zs[tid * 4] = *(const float4*)&z[b * 512 + tid * 4];
  __syncthreads();
  float acc = 0.f;
#pragma unroll 8
  for (int k = 0; k < 512; k++) acc += zs[k] * fc1_wt[k * 128 + tid];
  h1[tid] = fmaxf(acc + fc1_b[tid], 0.f);
  __syncthreads();
  if (tid < 32) {
    float a2 = 0.f;
#pragma unroll 8
    for (int k = 0; k < 128; k++) a2 += h1[k] * fc2_wt[k * 32 + tid];
    h2[tid] = fmaxf(a2 + fc2_b[tid], 0.f);
  }
  __syncthreads();
  if (tid < 2) {
    float a3 = 0.f;
#pragma unroll
    for (int k = 0; k < 32; k++) a3 += h2[k] * fc3_wt[k * 2 + tid];
    out[b * 2 + tid] = fmaxf(a3 + fc3_b[tid], 0.f);
  }
}

// ---------------------------------------------------------------------------
extern "C" void kernel_launch(void* const* d_in, const int* in_sizes, int n_in,
                              void* d_out, int out_size, void* d_ws, size_t ws_size,
                              hipStream_t stream) {
  const float* x     = (const float*)d_in[0];
  const float* w_ih  = (const float*)d_in[1];
  const float* w_hh  = (const float*)d_in[2];
  const float* b_ih  = (const float*)d_in[3];
  const float* b_hh  = (const float*)d_in[4];
  const float* w1    = (const float*)d_in[5];
  const float* b1    = (const float*)d_in[6];
  const float* w2    = (const float*)d_in[7];
  const float* b2    = (const float*)d_in[8];
  const float* w3    = (const float*)d_in[9];
  const float* b3    = (const float*)d_in[10];
  const float* w4    = (const float*)d_in[11];
  const float* b4    = (const float*)d_in[12];
  const float* fc1_w = (const float*)d_in[13];
  const float* fc1_b = (const float*)d_in[14];
  const float* fc2_w = (const float*)d_in[15];
  const float* fc2_b = (const float*)d_in[16];
  const float* fc3_w = (const float*)d_in[17];
  const float* fc3_b = (const float*)d_in[18];
  float* out = (float*)d_out;

  const size_t gfull = (size_t)65536 * 1024, gchunk = (size_t)8192 * 1024;
  const size_t xsf = (size_t)XSP;  // xs = 2*XSP halfs = XSP floats
  const size_t rest = 262144 + 1024 + 3 * 131072 + 262144 + 8388608 + 1048576 +
                      2097152 + 81920 + 49152 + 4096 + 65536 + 4096 + 64 + 786432;
  int full = (ws_size >= (gfull + xsf + rest) * 4) ? 1 : 0;
  size_t gsz = full ? gfull : gchunk;

  float* W = (float*)d_ws;
  size_t o = 0;
  float* gates  = W + o; o += gsz;
  float* w_q    = W + o; o += 262144;
  float* biasg  = W + o; o += 1024;
  float* h_st   = W + o; o += 131072;
  float* c_st   = W + o; o += 131072;
  float* hsum   = W + o; o += 131072;
  float* z      = W + o; o += 262144;
  float* out1   = W + o; o += (size_t)512 * 256 * 64;
  float* out2   = W + o; o += (size_t)512 * 64 * 32;
  float* out3   = W + o; o += (size_t)512 * 256 * 16;
  float* w2t    = W + o; o += 81920;
  float* w3t    = W + o; o += 49152;
  float* w4t    = W + o; o += 4096;
  float* fc1_wt = W + o; o += 65536;
  float* fc2_wt = W + o; o += 4096;
  float* fc3_wt = W + o; o += 64;
  _Float16* wihs = (_Float16*)(W + o); o += 786432;  // 2x1024x768 halfs
  _Float16* xs   = (_Float16*)(W + o); o += xsf;     // 2x65536x768 halfs
  // w1 fp16 split (5.5 MB) aliases out3 (8.4 MB): conv1 reads it strictly
  // before conv3 writes out3 (stream order), so the overlap is safe.
  _Float16* w1s = (_Float16*)out3;
  (void)in_sizes; (void)n_in; (void)out_size;

  xsplit_kernel<<<24576, 256, 0, stream>>>(x, xs);
  prep_kernel<<<5376, 256, 0, stream>>>(w_ih, w_hh, b_ih, b_hh, w1, w2, w3, w4,
                                        fc1_w, fc2_w, fc3_w,
                                        w_q, biasg, w1s, wihs, w2t, w3t, w4t,
                                        fc1_wt, fc2_wt, fc3_wt);
  if (full) {
    gemm_gates_mfma<<<4096, 256, 0, stream>>>(xs, wihs, biasg, gates, 0, 0);
    lstm_full<<<128, 1024, 0, stream>>>(gates, w_q, z);
  } else {
    for (int c = 0; c < NCHUNK; c++) {
      gemm_gates_mfma<<<512, 256, 0, stream>>>(xs, wihs, biasg, gates, c * TCHUNK, 1);
      lstm_chunk<<<128, 512, 0, stream>>>(gates, w_q, h_st, c_st, hsum, z,
                                          c == 0, c == NCHUNK - 1, 16, 0);
    }
  }
  conv1_mfma<<<dim3(4, 512), 256, 0, stream>>>(xs, w1s, b1, out1);
  conv2_kernel<<<512, 256, 0, stream>>>(out1, w2t, b2, out2);
  conv3_kernel<<<512, 256, 0, stream>>>(out2, w3t, b3, out3);
  conv4_kernel<<<512, 256, 0, stream>>>(out3, w4t, b4, z);
  head_kernel<<<512, 128, 0, stream>>>(z, fc1_wt, fc1_b, fc2_wt, fc2_b, fc3_wt, fc3_b, out);
}